// Round 9
// baseline (285.247 us; speedup 1.0000x reference)
//
#include <hip/hip_runtime.h>

// T1: (P=4, B=8192, C=128, 3, 3) fp32
// T2: (1, B, C, 3, 3) fp32 (broadcast over P)
// out[p,b,c,i,j] = sum_k T1[p,b,c,i,k] * T2[0,b,c,k,j]
//
// R11: R9/R10 proved cache-policy store overrides are unusable here (harness
// memsets the output through the cached path; bypassing stores lose to dirty
// zero-line evictions -> stale data). Plain cached stores only.
// Remaining hypothesis for the 1.42-1.50 TB/s write-rate pin: SHORT-LIVED
// WAVES. All six passing variants retire waves right after their store
// burst; a wave can't retire until stores ack (implicit drain at s_endpgm),
// so CU slots recycle through a ~10us congested store-ack wait ->
// throughput = slots/latency, masquerading as a rate cap. The 3.15 TB/s
// copy ubench uses few LONG-LIVED grid-stride blocks - never tested here
// in pure form (R2 had 4 iters but drained vmcnt(0) at every barrier).
// This version: 2048 persistent blocks (8/CU), each striding 8 (p,chunk)
// units; loads of unit i+1 issued BEFORE unit i's stores (loads stay older
// than all stores); zero explicit waits; single implicit drain at endpgm.
// ~18KB of stores per wave cumulatively in flight vs 2-9KB before.

typedef float floatx4 __attribute__((ext_vector_type(4)));

__global__ __launch_bounds__(256) void tc33_kernel(const float* __restrict__ T1,
                                                   const float* __restrict__ T2,
                                                   float* __restrict__ out) {
    __shared__ float so[2304];                 // 4 wave-private 576-float slices
    const long long PER_P = 9LL * 8192 * 128;  // floats per p-slice
    const int tid = threadIdx.x;
    const int w = tid >> 6;                    // wave id within block
    const int l = tid & 63;                    // lane
    float* slice = so + w * 576;
    floatx4* S4  = reinterpret_cast<floatx4*>(slice);

    // Each block owns 8 consecutive units: unit = blockIdx.x*8 + it.
    // unit -> p = unit>>12 (slow), chunk = unit&4095 -> contiguous 72KB
    // output region per block, dense device-wide sweep.
    const int unit0 = blockIdx.x * 8;

    // ---- prime unit0 loads ----
    long long cb, ab;
    {
        const int p = unit0 >> 12, chunk = unit0 & 4095;
        cb = (long long)chunk * 2304 + tid * 9;
        ab = (long long)p * PER_P + cb;
    }
    floatx4 vb0 = *reinterpret_cast<const floatx4*>(T2 + cb);
    floatx4 vb1 = *reinterpret_cast<const floatx4*>(T2 + cb + 4);
    float   vb8 = T2[cb + 8];
    floatx4 va0 = *reinterpret_cast<const floatx4*>(T1 + ab);
    floatx4 va1 = *reinterpret_cast<const floatx4*>(T1 + ab + 4);
    float   va8 = T1[ab + 8];

    #pragma unroll
    for (int it = 0; it < 8; ++it) {
        const int unit = unit0 + it;
        const int p = unit >> 12, chunk = unit & 4095;
        const long long wbase =
            (long long)p * PER_P + (long long)chunk * 2304 + (long long)w * 576;

        // Snapshot current unit's operands from the prefetch registers.
        float b[9], a[9];
        b[0] = vb0.x; b[1] = vb0.y; b[2] = vb0.z; b[3] = vb0.w;
        b[4] = vb1.x; b[5] = vb1.y; b[6] = vb1.z; b[7] = vb1.w;
        b[8] = vb8;
        a[0] = va0.x; a[1] = va0.y; a[2] = va0.z; a[3] = va0.w;
        a[4] = va1.x; a[5] = va1.y; a[6] = va1.z; a[7] = va1.w;
        a[8] = va8;

        // Issue next unit's loads NOW (older than this unit's stores; their
        // latency hides under this unit's compute + staging + stores).
        if (it < 7) {
            const int nu = unit + 1;
            const int np = nu >> 12, nc = nu & 4095;
            const long long ncb = (long long)nc * 2304 + tid * 9;
            const long long nab = (long long)np * PER_P + ncb;
            vb0 = *reinterpret_cast<const floatx4*>(T2 + ncb);
            vb1 = *reinterpret_cast<const floatx4*>(T2 + ncb + 4);
            vb8 = T2[ncb + 8];
            va0 = *reinterpret_cast<const floatx4*>(T1 + nab);
            va1 = *reinterpret_cast<const floatx4*>(T1 + nab + 4);
            va8 = T1[nab + 8];
        }

        float o[9];
        #pragma unroll
        for (int i = 0; i < 3; ++i) {
            #pragma unroll
            for (int j = 0; j < 3; ++j) {
                float s = a[i * 3 + 0] * b[0 * 3 + j];
                s = fmaf(a[i * 3 + 1], b[1 * 3 + j], s);
                s = fmaf(a[i * 3 + 2], b[2 * 3 + j], s);
                o[i * 3 + j] = s;
            }
        }

        // Wave-private transpose staging (stride-9 = 2 lanes/bank, free).
        #pragma unroll
        for (int i = 0; i < 9; ++i) slice[l * 9 + i] = o[i];

        __builtin_amdgcn_wave_barrier();  // DS pipe is in-order per wave

        floatx4 s0 = S4[l];
        floatx4 s1 = S4[l + 64];
        floatx4 s2;
        if (l < 16) s2 = S4[l + 128];

        // Fire-and-forget cached stores; nothing waits on them until endpgm.
        floatx4* O4 = reinterpret_cast<floatx4*>(out + wbase);
        O4[l]      = s0;
        O4[l + 64] = s1;
        if (l < 16) O4[l + 128] = s2;

        __builtin_amdgcn_wave_barrier();  // keep slice reads ahead of next
                                          // iteration's slice writes
    }
}

extern "C" void kernel_launch(void* const* d_in, const int* in_sizes, int n_in,
                              void* d_out, int out_size, void* d_ws, size_t ws_size,
                              hipStream_t stream) {
    const float* T1 = (const float*)d_in[0];
    const float* T2 = (const float*)d_in[1];
    float* out = (float*)d_out;

    // 16384 (p,chunk) units; 8 units per persistent block -> 2048 blocks
    // (exactly 8 blocks/CU on 256 CUs).
    const int threads = 256;
    const int blocks = 2048;
    tc33_kernel<<<blocks, threads, 0, stream>>>(T1, T2, out);
}

// Round 10
// 284.798 us; speedup vs baseline: 1.0016x; 1.0016x over previous
//
#include <hip/hip_runtime.h>

// T1: (P=4, B=8192, C=128, 3, 3) fp32
// T2: (1, B, C, 3, 3) fp32 (broadcast over P)
// out[p,b,c,i,j] = sum_k T1[p,b,c,i,k] * T2[0,b,c,k,j]
//
// R12: seven structures (incl. R11 persistent deep-store-queue waves) all
// pin at ~100us with write drain 1.38-1.50 TB/s invariant; reads vary
// freely; waves idle ~94% of lifetime -> a saturated queue inflates memory
// latency ~20k cycles. Last untested mechanism: L2 fill/evict interference.
// Output lines allocate DIRTY in the 4MB/XCD L2; the zero-reuse T1 read
// stream (151 MB) continuously evicts them, so every fill drags a dirty
// writeback on the same banks/victim queue -> fills + writebacks serialize;
// write rate == victim-queue service rate (pinned), load latency balloons.
// Test: R8 byte-identical but T1 loads are __builtin_nontemporal_load
// (no-allocate/LRU hint on LOADS - correctness-safe). T1 never pollutes
// L2; L2 holds T2 (reused) + output dirty lines. T2 stays cached.

typedef float floatx4 __attribute__((ext_vector_type(4)));

__global__ __launch_bounds__(256) void tc33_kernel(const float* __restrict__ T1,
                                                   const float* __restrict__ T2,
                                                   float* __restrict__ out) {
    __shared__ float so[2304];                 // 4 wave-private 576-float slices
    const long long PER_P = 9LL * 8192 * 128;  // floats per p-slice
    const int tid = threadIdx.x;
    const int w = tid >> 6;                    // wave id within block
    const int l = tid & 63;                    // lane
    const int bid = blockIdx.x;
    const int p = bid >> 12;                   // slow index: one p per block
    const int chunk = bid & 4095;
    const long long chunkBase = (long long)chunk * 2304;   // floats
    const long long cbase = chunkBase + tid * 9;           // this thread's cell
    const long long abase = (long long)p * PER_P + cbase;  // A cell offset
    const long long wbase = (long long)p * PER_P + chunkBase + (long long)w * 576;

    float* slice = so + w * 576;
    floatx4* S4  = reinterpret_cast<floatx4*>(slice);

    // ---- T2 (cached: real reuse across p) ----
    floatx4 vb0 = *reinterpret_cast<const floatx4*>(T2 + cbase);
    floatx4 vb1 = *reinterpret_cast<const floatx4*>(T2 + cbase + 4);
    float   vb8 = T2[cbase + 8];
    // ---- T1 (nontemporal: pure stream, zero reuse -> don't allocate L2) ----
    floatx4 va0 = __builtin_nontemporal_load(reinterpret_cast<const floatx4*>(T1 + abase));
    floatx4 va1 = __builtin_nontemporal_load(reinterpret_cast<const floatx4*>(T1 + abase + 4));
    float   va8 = __builtin_nontemporal_load(T1 + abase + 8);

    float b[9], a[9];
    b[0] = vb0.x; b[1] = vb0.y; b[2] = vb0.z; b[3] = vb0.w;
    b[4] = vb1.x; b[5] = vb1.y; b[6] = vb1.z; b[7] = vb1.w;
    b[8] = vb8;
    a[0] = va0.x; a[1] = va0.y; a[2] = va0.z; a[3] = va0.w;
    a[4] = va1.x; a[5] = va1.y; a[6] = va1.z; a[7] = va1.w;
    a[8] = va8;

    float o[9];
    #pragma unroll
    for (int i = 0; i < 3; ++i) {
        #pragma unroll
        for (int j = 0; j < 3; ++j) {
            float s = a[i * 3 + 0] * b[0 * 3 + j];
            s = fmaf(a[i * 3 + 1], b[1 * 3 + j], s);
            s = fmaf(a[i * 3 + 2], b[2 * 3 + j], s);
            o[i * 3 + j] = s;
        }
    }

    // Wave-private transpose staging (stride-9 = 2 lanes/bank, conflict-free).
    #pragma unroll
    for (int i = 0; i < 9; ++i) slice[l * 9 + i] = o[i];

    __builtin_amdgcn_wave_barrier();  // DS pipe is in-order per wave

    // Coalesced read-back and single contiguous cached store burst.
    floatx4 s0 = S4[l];
    floatx4 s1 = S4[l + 64];
    floatx4 s2;
    if (l < 16) s2 = S4[l + 128];

    floatx4* O4 = reinterpret_cast<floatx4*>(out + wbase);
    O4[l]      = s0;
    O4[l + 64] = s1;
    if (l < 16) O4[l + 128] = s2;
}

extern "C" void kernel_launch(void* const* d_in, const int* in_sizes, int n_in,
                              void* d_out, int out_size, void* d_ws, size_t ws_size,
                              hipStream_t stream) {
    const float* T1 = (const float*)d_in[0];
    const float* T2 = (const float*)d_in[1];
    float* out = (float*)d_out;

    // 4 p-slices x 4096 chunks; one (p, chunk) per 256-thread block.
    const int threads = 256;
    const int blocks = 4 * 4096;  // 16384
    tc33_kernel<<<blocks, threads, 0, stream>>>(T1, T2, out);
}